// Round 4
// baseline (576.821 us; speedup 1.0000x reference)
//
#include <hip/hip_runtime.h>
#include <hip/hip_bf16.h>

// PixelContrastLossOnlyNeg on MI355X.
// feats [16,256,128,128] f32, queue [256,256] f32, labels [262144,256] i32 -> scalar f32.
// R4: two-kernel pipeline. (1) lcomp: labels 256MB -> 8MB bitmask planes
// (streaming). (2) pcl_main: persistent double-buffered tile loop, 512-thr
// blocks, stage(t+1) in flight during K-loop(t); epilogue is pure VALU on
// register masks. Memory floor: 256MB (lcomp) + 264MB (main) ~ 83us total.

typedef __bf16 bf16x8 __attribute__((ext_vector_type(8)));
typedef float floatx4 __attribute__((ext_vector_type(4)));

#define N_PIX 262144

// Pack two f32 -> two bf16 (round-half-up).
__device__ __forceinline__ unsigned int pack_bf2(float a, float b) {
  unsigned int ua = __float_as_uint(a) + 0x8000u;
  unsigned int ub = __float_as_uint(b) + 0x8000u;
  return (ua >> 16) | (ub & 0xffff0000u);
}

// ---------------------------------------------------------------------------
// k0: queue f32 -> bf16 * (1/T), pre-swizzled in A-fragment lane order.
// Also zeroes global accumulators.
// ---------------------------------------------------------------------------
__global__ void qprep(const float* __restrict__ queue,
                      unsigned short* __restrict__ qs,
                      float* __restrict__ accum) {
  const int gt = blockIdx.x * 256 + threadIdx.x;  // 0..8191
  const int t = gt >> 6;
  const int lane = gt & 63;
  const int m = ((t >> 3) << 4) | (lane & 15);
  const int k0 = ((t & 7) << 5) | ((lane >> 4) << 3);
  const float* qr = queue + m * 256 + k0;
  const float TINV = 14.2857142857142857f;
  union { unsigned int u32[4]; uint4 v; } u;
#pragma unroll
  for (int j = 0; j < 4; ++j)
    u.u32[j] = pack_bf2(qr[2 * j] * TINV, qr[2 * j + 1] * TINV);
  *(uint4*)(qs + (size_t)gt * 8) = u.v;
  if (gt == 0) { accum[0] = 0.0f; accum[1] = 0.0f; }
}

// ---------------------------------------------------------------------------
// k1: label compress. labels[N_PIX][256] i32 -> maskT[8][N_PIX] u32 planes,
// plane j bit b (of word maskT[j][p]) = (labels[p][32j+b] != 0).
// One wave per 64 pixels; per pixel: 1KB coalesced load (lane L holds classes
// 4L..4L+3), nibble, shfl-OR over groups of 8 lanes, lane 8j stores word j.
// ---------------------------------------------------------------------------
__global__ __launch_bounds__(256) void lcomp(const int* __restrict__ labels,
                                             unsigned* __restrict__ maskT) {
  const int tid = threadIdx.x;
  const int lane = tid & 63;
  const int wave = (blockIdx.x << 2) + (tid >> 6);
  const int p0 = wave << 6;  // 64 pixels per wave
  const int* lb = labels + ((size_t)p0 << 8) + (lane << 2);
  const int sh = (lane & 7) << 2;
  const bool writer = (lane & 7) == 0;
  unsigned* wp = maskT + ((size_t)(lane >> 3) * N_PIX) + p0;

#pragma unroll
  for (int c8 = 0; c8 < 8; ++c8) {
    int4 lv[8];
#pragma unroll
    for (int i = 0; i < 8; ++i)
      lv[i] = *(const int4*)(lb + (((c8 << 3) + i) << 8));
#pragma unroll
    for (int i = 0; i < 8; ++i) {
      unsigned v = ((lv[i].x != 0) ? 1u : 0u) | ((lv[i].y != 0) ? 2u : 0u) |
                   ((lv[i].z != 0) ? 4u : 0u) | ((lv[i].w != 0) ? 8u : 0u);
      v <<= sh;
      v |= __shfl_xor(v, 1);
      v |= __shfl_xor(v, 2);
      v |= __shfl_xor(v, 4);
      if (writer) wp[(c8 << 3) + i] = v;
    }
  }
}

// ---------------------------------------------------------------------------
// k2: main fused kernel. 1024 blocks x 512 threads (8 waves), each block owns
// 4 consecutive 64-pixel tiles, double-buffered LDS. Wave w owns classes
// [32w, 32w+32). Per tile: issue stage(t+1) -> K-loop(t) -> epilogue(t) ->
// pack(t+1) -> barrier.
// ---------------------------------------------------------------------------
__global__ __launch_bounds__(512, 4) void pcl_main(
    const float* __restrict__ feats,
    const unsigned* __restrict__ maskT,
    const unsigned short* __restrict__ qs,
    float* __restrict__ accum) {
  __shared__ uint4 Bs[2][2048];    // 64 KB: double-buffered bf16 B-frags
  __shared__ float Red[16][64];    // 4 KB: per-wave nn/pp partials

  const int tid = threadIdx.x;
  const int w = tid >> 6;          // wave 0..7
  const int lane = tid & 63;
  const int qd = lane >> 4;
  const int s = lane & 15;
  const int T0 = blockIdx.x << 2;  // first tile of 4

  const bf16x8* qfrag = (const bf16x8*)qs;
  const int chB = (w << 5) + ((lane >> 4) << 3);  // base channel for staging
  const int px4 = (lane & 15) << 2;               // base pixel (of 4)
  const int kg = (w << 2) + (lane >> 4);          // k-group 0..31 for pack
  const unsigned* mp = maskT + (size_t)w * N_PIX;

  floatx4 frv[8];       // staged feats: 8 channels x 4 pixels
  unsigned mk[2][4];    // double-buffered masks (4 pixels each)
  float lacc = 0.0f, cacc = 0.0f;

#define ISSUE_TILE(T, MB)                                                     \
  do {                                                                        \
    const float* fb = feats + ((size_t)((T) >> 8) << 22) + (((T) & 255) << 6);\
    _Pragma("unroll") for (int j = 0; j < 8; ++j)                             \
        frv[j] = *(const floatx4*)(fb + (size_t)(chB + j) * 16384 + px4);     \
    _Pragma("unroll") for (int nt = 0; nt < 4; ++nt)                          \
        mk[MB][nt] = mp[((T) << 6) + (nt << 4) + s];                          \
  } while (0)

#define PACK_TILE(BUF)                                                        \
  do {                                                                        \
    _Pragma("unroll") for (int jj = 0; jj < 4; ++jj) {                        \
      const int n = px4 + jj;                                                 \
      uint4 u;                                                                \
      u.x = pack_bf2(frv[0][jj], frv[1][jj]);                                 \
      u.y = pack_bf2(frv[2][jj], frv[3][jj]);                                 \
      u.z = pack_bf2(frv[4][jj], frv[5][jj]);                                 \
      u.w = pack_bf2(frv[6][jj], frv[7][jj]);                                 \
      Bs[BUF][(((kg >> 2) << 2) + (n >> 4)) * 64 + ((kg & 3) << 4) + (n & 15)] = u; \
    }                                                                         \
  } while (0)

  // prologue: stage tile T0 into Bs[0]
  ISSUE_TILE(T0, 0);
  PACK_TILE(0);
  __syncthreads();

  for (int t = 0; t < 4; ++t) {
    const int cur = t & 1;
    if (t < 3) ISSUE_TILE(T0 + t + 1, 1 - cur);   // in flight during K-loop

    // ---- K-loop: wave w computes classes [32w,32w+32) x 64 pixels ----
    floatx4 acc[2][4];
#pragma unroll
    for (int mt = 0; mt < 2; ++mt)
#pragma unroll
      for (int nt = 0; nt < 4; ++nt)
        acc[mt][nt] = floatx4{0.0f, 0.0f, 0.0f, 0.0f};

    const bf16x8* Bf = (const bf16x8*)Bs[cur];
#pragma unroll
    for (int mt = 0; mt < 2; ++mt) {
      const int m16 = (w << 1) + mt;
#pragma unroll
      for (int kh = 0; kh < 2; ++kh) {
        bf16x8 af[4];
#pragma unroll
        for (int kk = 0; kk < 4; ++kk)
          af[kk] = qfrag[(((m16 << 3) + (kh << 2) + kk) << 6) + lane];
#pragma unroll
        for (int kk = 0; kk < 4; ++kk) {
          const int ks = (kh << 2) + kk;
#pragma unroll
          for (int nt = 0; nt < 4; ++nt) {
            const bf16x8 bv = Bf[(((ks << 2) + nt) << 6) + lane];
            acc[mt][nt] = __builtin_amdgcn_mfma_f32_16x16x32_bf16(
                af[kk], bv, acc[mt][nt], 0, 0, 0);
          }
        }
      }
    }

    // ---- epilogue: pure VALU, mask bit = mt*16 + qd*4 + r of plane w ----
    float nn[4] = {0.f, 0.f, 0.f, 0.f};
    float pp[4] = {0.f, 0.f, 0.f, 0.f};
#pragma unroll
    for (int mt = 0; mt < 2; ++mt) {
#pragma unroll
      for (int nt = 0; nt < 4; ++nt) {
        const floatx4 a = acc[mt][nt];
        const unsigned mw = mk[cur][nt];
#pragma unroll
        for (int r = 0; r < 4; ++r) {
          const unsigned p = (mw >> ((mt << 4) + (qd << 2) + r)) & 1u;
          const float ls = __uint_as_float(__float_as_uint(a[r]) ^ (p << 31));
          const float e = __expf(ls);
          nn[nt] += p ? 0.0f : e;
          pp[nt] += p ? e : 0.0f;
        }
      }
    }
#pragma unroll
    for (int nt = 0; nt < 4; ++nt) {
      nn[nt] += __shfl_xor(nn[nt], 16);
      nn[nt] += __shfl_xor(nn[nt], 32);
      pp[nt] += __shfl_xor(pp[nt], 16);
      pp[nt] += __shfl_xor(pp[nt], 32);
    }
    if (lane < 16) {
#pragma unroll
      for (int nt = 0; nt < 4; ++nt) {
        Red[(w << 1) | 0][(nt << 4) + lane] = nn[nt];
        Red[(w << 1) | 1][(nt << 4) + lane] = pp[nt];
      }
    }
    __syncthreads();

    if (tid < 64) {
      float sn = 0.f, sp = 0.f;
#pragma unroll
      for (int ww = 0; ww < 8; ++ww) {
        sn += Red[(ww << 1) | 0][tid];
        sp += Red[(ww << 1) | 1][tid];
      }
      const float loss = logf(sn * sp + 1.0f);
      lacc += loss;
      cacc += (loss != 0.0f) ? 1.0f : 0.0f;
    }

    if (t < 3) PACK_TILE(1 - cur);  // vmcnt drain waits only the staged feats
    __syncthreads();
  }

  // wave 0 (tid<64) holds per-pixel losses across 4 tiles: reduce + 2 atomics
  if (tid < 64) {
#pragma unroll
    for (int off = 32; off > 0; off >>= 1) {
      lacc += __shfl_xor(lacc, off);
      cacc += __shfl_xor(cacc, off);
    }
    if (tid == 0) {
      atomicAdd(&accum[0], lacc);
      atomicAdd(&accum[1], cacc);
    }
  }
#undef ISSUE_TILE
#undef PACK_TILE
}

// ---------------------------------------------------------------------------
// k3: scalar finalize.
// ---------------------------------------------------------------------------
__global__ void pcl_finalize(const float* __restrict__ accum,
                             float* __restrict__ out) {
  const float ssum = accum[0];
  const float c = accum[1];
  out[0] = (c != 0.0f) ? (ssum / c) : 0.0f;
}

extern "C" void kernel_launch(void* const* d_in, const int* in_sizes, int n_in,
                              void* d_out, int out_size, void* d_ws, size_t ws_size,
                              hipStream_t stream) {
  (void)in_sizes; (void)n_in; (void)out_size; (void)ws_size;
  const float* feats = (const float*)d_in[0];
  const float* queue = (const float*)d_in[1];
  const int* labels = (const int*)d_in[2];

  // ws layout: [0, 8MB) maskT (8 planes x 262144 u32); [8MB, +128KB) qs;
  // then accum (2 floats).
  unsigned* maskT = (unsigned*)d_ws;
  unsigned short* qs = (unsigned short*)((char*)d_ws + (size_t)8 * N_PIX * 4);
  float* accum = (float*)((char*)qs + 256 * 256 * sizeof(unsigned short));

  lcomp<<<1024, 256, 0, stream>>>(labels, maskT);
  qprep<<<32, 256, 0, stream>>>(queue, qs, accum);
  pcl_main<<<1024, 512, 0, stream>>>(feats, maskT, qs, accum);
  pcl_finalize<<<1, 1, 0, stream>>>(accum, (float*)d_out);
}